// Round 13
// baseline (493.130 us; speedup 1.0000x reference)
//
#include <hip/hip_runtime.h>
#include <float.h>

// VectorQuantize: h=8 heads, c=2048 codes, d=64, b=8, t=2048 (n=16384 vec/head)
#define H   8
#define C   2048
#define D   64
#define NPH 16384     // vectors per head (b*t)
#define HD  512       // h*d
#define DECAYF 0.9f
#define DELTA 3.0f    // candidate margin >= 2x worst-case bf16 score error (~0.6)
#define CAP 64        // per-vector candidate slots
#define VB  128       // vectors per block (R13: was 256; 1024 blocks -> 4 blocks/CU)

typedef __attribute__((ext_vector_type(8))) short short8v;   // 8 bf16 (4 VGPR)
typedef __attribute__((ext_vector_type(4))) float f32x4;

__device__ inline unsigned short f32_to_bf16_rne(float f) {
    unsigned int x = __float_as_uint(f);
    return (unsigned short)((x + 0x7FFFu + ((x >> 16) & 1u)) >> 16);
}

// ---------------------------------------------------------------------------
// Kernel 0: e_sq[h,c] = sum_d ke[h,c,d]^2
// ---------------------------------------------------------------------------
__global__ __launch_bounds__(256) void vq_esq_kernel(const float* __restrict__ ke,
                                                     float* __restrict__ esq) {
    int i = blockIdx.x * 256 + threadIdx.x;
    const float* e = ke + (size_t)i * D;
    float s = 0.f;
#pragma unroll
    for (int d = 0; d < D; ++d) s = fmaf(e[d], e[d], s);
    esq[i] = s;
}

// ---------------------------------------------------------------------------
// Kernel 0b: keb = bf16(ke)
// ---------------------------------------------------------------------------
__global__ __launch_bounds__(256) void vq_keb_kernel(const float* __restrict__ ke,
                                                     unsigned short* __restrict__ keb) {
    int i = blockIdx.x * 256 + threadIdx.x;   // H*C*D = 1048576
    keb[i] = f32_to_bf16_rne(ke[i]);
}

// ---------------------------------------------------------------------------
// Kernel 1: MFMA screening + exact rescore (R12 math verbatim).
//   R13: (a) depth-4 software-pipelined B/esq prefetch (R12 was depth-1:
//   ~200cyc L2 latency vs 38cyc MFMA/chunk -> MfmaUtil 14%); (b) 1024 blocks
//   x 128 vec -> 4 blocks/CU (R12: 512 blocks = 2/CU, Occupancy 22%);
//   (c) histogram fused into tail (direct atomicAdd on counts; vq_hist
//   kernel dropped). Wave w owns vecs w*32..+31 (2 16-tiles). Candidate
//   collection per-VECTOR (R10 lesson); exact f32 rescore per vec, serial
//   fmaf k-ascending, fmaf(-2,dot,esq); lexicographic (score,idx) min;
//   ccnt>CAP -> deterministic full exact scan fallback.
// ---------------------------------------------------------------------------
__global__ __launch_bounds__(256, 2)
void vq_main_kernel(const float* __restrict__ x,
                    const unsigned short* __restrict__ keb,
                    const float* __restrict__ ke,
                    const float* __restrict__ esq,
                    float* __restrict__ outq,
                    float* __restrict__ outi,
                    unsigned short* __restrict__ indw,
                    unsigned int* __restrict__ counts) {
    __shared__ int            ccnt[VB];
    __shared__ unsigned short cand[VB][CAP];
    __shared__ int            sidx[VB];

    const int tid  = threadIdx.x;
    const int lane = tid & 63;
    const int w    = __builtin_amdgcn_readfirstlane(tid >> 6);
    const int h    = blockIdx.x & 7;
    const int n0   = (blockIdx.x >> 3) * VB;

    const unsigned short* kebh = keb + (size_t)h * C * D;
    const float* keh  = ke  + (size_t)h * C * D;
    const float* esqh = esq + (size_t)h * C;

    if (tid < VB) ccnt[tid] = 0;
    __syncthreads();

    const int col = lane & 15;        // code col / vec row within 16-tile
    const int kg  = (lane >> 4) * 8;  // this lane's k-group base

    // ---- A-frags: lane's 2 vec-rows x 64 k, bf16, persistent ----
    short8v afr[2][2];
#pragma unroll
    for (int vt = 0; vt < 2; ++vt) {
        const float* xp = x + (size_t)(n0 + w * 32 + vt * 16 + col) * HD
                            + (size_t)h * D + kg;
#pragma unroll
        for (int kf = 0; kf < 2; ++kf) {
            float4 u0 = *(const float4*)(xp + kf * 32);
            float4 u1 = *(const float4*)(xp + kf * 32 + 4);
            short8v a;
            a[0] = (short)f32_to_bf16_rne(u0.x); a[1] = (short)f32_to_bf16_rne(u0.y);
            a[2] = (short)f32_to_bf16_rne(u0.z); a[3] = (short)f32_to_bf16_rne(u0.w);
            a[4] = (short)f32_to_bf16_rne(u1.x); a[5] = (short)f32_to_bf16_rne(u1.y);
            a[6] = (short)f32_to_bf16_rne(u1.z); a[7] = (short)f32_to_bf16_rne(u1.w);
            afr[vt][kf] = a;
        }
    }

    float amin[8];
#pragma unroll
    for (int s = 0; s < 8; ++s) amin[s] = FLT_MAX;

#define LOADB16(CB, B0, B1, EQ)                                                \
    {                                                                          \
        const unsigned short* kb = kebh + (size_t)((CB) + col) * D + kg;       \
        B0 = *(const short8v*)(kb);                                            \
        B1 = *(const short8v*)(kb + 32);                                       \
        EQ = esqh[(CB) + col];                                                 \
    }

    // ================= pass 1: per-vector approx min (depth-4 pipeline) ====
    {
        short8v pa[4], pb[4]; float pq[4];
#pragma unroll
        for (int i = 0; i < 4; ++i) LOADB16(i << 4, pa[i], pb[i], pq[i]);
#pragma unroll 1
        for (int g = 0; g < 32; ++g) {
#pragma unroll
            for (int i = 0; i < 4; ++i) {
                const short8v c0 = pa[i], c1 = pb[i];
                const float   q  = pq[i];
                const int nch = ((g * 4 + i + 4) & 127) << 4;   // wrapped tail: harmless
                LOADB16(nch, pa[i], pb[i], pq[i]);
#pragma unroll
                for (int vt = 0; vt < 2; ++vt) {
                    f32x4 acc = {0.f, 0.f, 0.f, 0.f};
                    acc = __builtin_amdgcn_mfma_f32_16x16x32_bf16(afr[vt][0], c0, acc, 0, 0, 0);
                    acc = __builtin_amdgcn_mfma_f32_16x16x32_bf16(afr[vt][1], c1, acc, 0, 0, 0);
#pragma unroll
                    for (int r = 0; r < 4; ++r) {
                        float sc = fmaf(-2.f, acc[r], q);
                        amin[vt * 4 + r] = fminf(amin[vt * 4 + r], sc);
                    }
                }
            }
        }
    }

    // cross-lane min over the 16 lanes sharing (lane>>4)
#pragma unroll
    for (int s = 0; s < 8; ++s) {
        float v = amin[s];
        v = fminf(v, __shfl_xor(v, 1));
        v = fminf(v, __shfl_xor(v, 2));
        v = fminf(v, __shfl_xor(v, 4));
        v = fminf(v, __shfl_xor(v, 8));
        amin[s] = v;
    }

    // ================= pass 2: collect candidates per VECTOR ================
    {
        short8v pa[4], pb[4]; float pq[4];
#pragma unroll
        for (int i = 0; i < 4; ++i) LOADB16(i << 4, pa[i], pb[i], pq[i]);
#pragma unroll 1
        for (int g = 0; g < 32; ++g) {
#pragma unroll
            for (int i = 0; i < 4; ++i) {
                const short8v c0 = pa[i], c1 = pb[i];
                const float   q  = pq[i];
                const int cb  = (g * 4 + i) << 4;
                const int nch = ((g * 4 + i + 4) & 127) << 4;
                LOADB16(nch, pa[i], pb[i], pq[i]);
#pragma unroll
                for (int vt = 0; vt < 2; ++vt) {
                    f32x4 acc = {0.f, 0.f, 0.f, 0.f};
                    acc = __builtin_amdgcn_mfma_f32_16x16x32_bf16(afr[vt][0], c0, acc, 0, 0, 0);
                    acc = __builtin_amdgcn_mfma_f32_16x16x32_bf16(afr[vt][1], c1, acc, 0, 0, 0);
#pragma unroll
                    for (int r = 0; r < 4; ++r) {
                        float sc = fmaf(-2.f, acc[r], q);
                        if (sc <= amin[vt * 4 + r] + DELTA) {
                            const int vec = w * 32 + vt * 16 + ((lane >> 4) << 2) + r;
                            int pos = atomicAdd(&ccnt[vec], 1);
                            if (pos < CAP) cand[vec][pos] = (unsigned short)(cb + col);
                        }
                    }
                }
            }
        }
    }
    __syncthreads();

    // ================= exact f32 rescore: thread tid <-> vec tid ============
    if (tid < VB) {
        const float4* xr = (const float4*)(x + (size_t)(n0 + tid) * HD + (size_t)h * D);
        const int nc = ccnt[tid];
        float bb = FLT_MAX;
        int   bi = 0x7fffffff;
        if (nc <= CAP) {
            for (int i = 0; i < nc; ++i) {
                const int code = cand[tid][i];
                const float4* er = (const float4*)(keh + (size_t)code * D);
                float s = 0.f;
#pragma unroll 4
                for (int kq = 0; kq < 16; ++kq) {
                    float4 a4 = xr[kq]; float4 e4 = er[kq];
                    s = fmaf(a4.x, e4.x, s); s = fmaf(a4.y, e4.y, s);
                    s = fmaf(a4.z, e4.z, s); s = fmaf(a4.w, e4.w, s);
                }
                float sc = fmaf(-2.f, s, esqh[code]);
                if (sc < bb || (sc == bb && code < bi)) { bb = sc; bi = code; }
            }
        } else {
            // deterministic fallback: full exact scan, ascending => first-min
            for (int code = 0; code < C; ++code) {
                const float4* er = (const float4*)(keh + (size_t)code * D);
                float s = 0.f;
#pragma unroll 4
                for (int kq = 0; kq < 16; ++kq) {
                    float4 a4 = xr[kq]; float4 e4 = er[kq];
                    s = fmaf(a4.x, e4.x, s); s = fmaf(a4.y, e4.y, s);
                    s = fmaf(a4.z, e4.z, s); s = fmaf(a4.w, e4.w, s);
                }
                float sc = fmaf(-2.f, s, esqh[code]);
                if (sc < bb) { bb = sc; bi = code; }
            }
        }
        sidx[tid] = bi;
        outi[(size_t)(n0 + tid) * H + h] = (float)bi;          // [b,t,h]
        indw[((size_t)h << 14) + n0 + tid] = (unsigned short)bi;
        atomicAdd(&counts[(h << 11) + bi], 1u);                // fused histogram
    }
    __syncthreads();

    // ---- gather quantized vectors (no atomics) ----
    {
        const int v  = tid >> 1;                 // 0..127
        const int db = (tid & 1) * 32;
        const int ci = sidx[v];
        const float* ev = keh + (size_t)ci * D + db;
        float* qo = outq + (size_t)(n0 + v) * HD + (size_t)h * D + db;
#pragma unroll
        for (int i = 0; i < 8; ++i)
            ((float4*)qo)[i] = ((const float4*)ev)[i];
    }
}

// ---------------------------------------------------------------------------
// Kernel 3: per-head exclusive prefix scan of counts -> off, cur
// ---------------------------------------------------------------------------
__global__ __launch_bounds__(256) void vq_scan_kernel(const unsigned int* __restrict__ counts,
                                                      unsigned int* __restrict__ off,
                                                      unsigned int* __restrict__ cur) {
    __shared__ unsigned int sa[C], sb[C];
    const int h   = blockIdx.x;
    const int tid = threadIdx.x;
#pragma unroll
    for (int j = 0; j < 8; ++j) sa[j * 256 + tid] = counts[(h << 11) + j * 256 + tid];
    __syncthreads();
    unsigned int* src = sa;
    unsigned int* dst = sb;
    for (int s = 1; s < C; s <<= 1) {
#pragma unroll
        for (int j = 0; j < 8; ++j) {
            const int c = j * 256 + tid;
            unsigned int v = src[c];
            if (c >= s) v += src[c - s];
            dst[c] = v;
        }
        __syncthreads();
        unsigned int* t = src; src = dst; dst = t;
    }
#pragma unroll
    for (int j = 0; j < 8; ++j) {
        const int c = j * 256 + tid;
        const unsigned int e = c ? src[c - 1] : 0u;
        off[(h << 11) + c] = e;
        cur[(h << 11) + c] = e;
    }
}

// ---------------------------------------------------------------------------
// Kernel 4: scatter vec-ids into per-code lists (131K cursor atomics)
// ---------------------------------------------------------------------------
__global__ __launch_bounds__(256) void vq_scatter_kernel(const unsigned short* __restrict__ ind,
                                                         unsigned int* __restrict__ cur,
                                                         unsigned short* __restrict__ perm) {
    const int g = blockIdx.x * 256 + threadIdx.x;   // 131072
    const int h = g >> 14;
    const int n = g & 16383;
    const int c = ind[g];
    const unsigned int pos = atomicAdd(&cur[(h << 11) + c], 1u);
    perm[((size_t)h << 14) + pos] = (unsigned short)n;
}

// ---------------------------------------------------------------------------
// Kernel 5: segmented reduce + fused EMA lerp. One wave per (head,code);
//   lane = d. f64 accumulation => order-independent after f32 rounding.
// ---------------------------------------------------------------------------
__global__ __launch_bounds__(256) void vq_reduce_kernel(const float* __restrict__ x,
                                                        const float* __restrict__ ke,
                                                        const unsigned short* __restrict__ perm,
                                                        const unsigned int* __restrict__ counts,
                                                        const unsigned int* __restrict__ off,
                                                        const int* __restrict__ ko,
                                                        float* __restrict__ outk) {
    const int tid  = threadIdx.x;
    const int lane = tid & 63;
    const int pair = blockIdx.x * 4 + (tid >> 6);   // == h*2048 + c
    const int h    = pair >> 11;

    const unsigned int cnt = counts[pair];
    const unsigned int o   = off[pair];
    const unsigned short* pl = perm + ((size_t)h << 14) + o;

    double acc = 0.0;
    for (unsigned int i = 0; i < cnt; ++i) {
        const int vid = pl[i];   // wave-uniform broadcast load
        acc += (double)x[(size_t)vid * HD + (size_t)h * D + lane];
    }
    const float esum = (float)acc;
    const float kv   = ke[(size_t)pair * D + lane];
    const float ov   = ko[0] ? (kv + DECAYF * (esum - kv)) : kv;
    outk[(size_t)pair * D + lane] = ov;
}

extern "C" void kernel_launch(void* const* d_in, const int* in_sizes, int n_in,
                              void* d_out, int out_size, void* d_ws, size_t ws_size,
                              hipStream_t stream) {
    const float* x  = (const float*)d_in[0];
    const float* ke = (const float*)d_in[1];
    const int*   ko = (const int*)d_in[2];

    float* out  = (float*)d_out;
    float* outq = out;                                   // 8,388,608 floats
    float* outi = out + (size_t)H * NPH * D;             // +131,072 floats
    float* outk = outi + (size_t)NPH * H;                // +1,048,576 floats

    // workspace layout
    float*          esq    = (float*)d_ws;                              // 16,384 f32
    unsigned short* keb    = (unsigned short*)(esq + H * C);            // 1M u16
    unsigned short* indw   = keb + (size_t)H * C * D;                   // 131,072 u16
    unsigned int*   counts = (unsigned int*)(indw + (size_t)H * NPH);   // 16,384 u32
    unsigned int*   offv   = counts + H * C;                            // 16,384 u32
    unsigned int*   curv   = offv + H * C;                              // 16,384 u32
    unsigned short* perm   = (unsigned short*)(curv + H * C);           // 131,072 u16

    hipMemsetAsync(counts, 0, (size_t)H * C * sizeof(unsigned int), stream);

    vq_esq_kernel<<<(H * C) / 256, 256, 0, stream>>>(ke, esq);
    vq_keb_kernel<<<(H * C * D) / 256, 256, 0, stream>>>(ke, keb);
    vq_main_kernel<<<1024, 256, 0, stream>>>(x, keb, ke, esq, outq, outi, indw, counts);
    vq_scan_kernel<<<H, 256, 0, stream>>>(counts, offv, curv);
    vq_scatter_kernel<<<512, 256, 0, stream>>>(indw, curv, perm);
    vq_reduce_kernel<<<(H * C) / 4, 256, 0, stream>>>(x, ke, perm, counts, offv, ko, outk);
}